// Round 1
// baseline (212.195 us; speedup 1.0000x reference)
//
#include <hip/hip_runtime.h>

typedef unsigned short u16;
typedef unsigned int u32;
typedef __attribute__((ext_vector_type(8))) __bf16 bf16x8;
typedef __attribute__((ext_vector_type(4))) float f32x4;

union U8 {
  bf16x8 b;
  uint2 u2[2];
  uint4 u4;
  u16 us[8];
};

__device__ __forceinline__ u16 f2bf(float f) {
  u32 x = __float_as_uint(f);
  x += 0x7FFFu + ((x >> 16) & 1u);
  return (u16)(x >> 16);
}
__device__ __forceinline__ float bf2f(u16 u) {
  return __uint_as_float(((u32)u) << 16);
}

// ---------------- f32 -> bf16 convert (vectorized) ----------------
__global__ void k_convert(const float* __restrict__ src, u16* __restrict__ dst, int n4) {
  int idx = blockIdx.x * blockDim.x + threadIdx.x;
  int stride = gridDim.x * blockDim.x;
  for (int i = idx; i < n4; i += stride) {
    float4 v = ((const float4*)src)[i];
    ushort4 o;
    o.x = f2bf(v.x); o.y = f2bf(v.y); o.z = f2bf(v.z); o.w = f2bf(v.w);
    ((ushort4*)dst)[i] = o;
  }
}

// ---------------- rel projection: (B*N*N, 32) @ (32,16)^T + b -> bf16 [b][h][n][m] ----------------
__global__ __launch_bounds__(256) void k_rel(const float* __restrict__ rb,
                                             const float* __restrict__ Wr,
                                             const float* __restrict__ br,
                                             u16* __restrict__ out) {
  __shared__ float Wl[16][32];
  __shared__ float bl[16];
  int t = threadIdx.x;
  ((float*)Wl)[t] = Wr[t];
  ((float*)Wl)[t + 256] = Wr[t + 256];
  if (t < 16) bl[t] = br[t];
  __syncthreads();

  size_t row = (size_t)blockIdx.x * 256 + t;  // < 2097152
  int m = (int)(row & 511);
  int n = (int)((row >> 9) & 511);
  int b = (int)(row >> 18);
  const float4* rp = (const float4*)(rb + row * 32);
  float4 r4[8];
#pragma unroll
  for (int j = 0; j < 8; ++j) r4[j] = rp[j];

  size_t obase = (size_t)b * 4194304 + (size_t)n * 512 + m;
#pragma unroll
  for (int h = 0; h < 16; ++h) {
    float acc = bl[h];
    const float* w = Wl[h];
#pragma unroll
    for (int j = 0; j < 8; ++j) {
      acc += r4[j].x * w[4 * j + 0] + r4[j].y * w[4 * j + 1] +
             r4[j].z * w[4 * j + 2] + r4[j].w * w[4 * j + 3];
    }
    out[obase + (size_t)h * 262144] = f2bf(acc);
  }
}

// ---------------- GEMM: C(M x N) = A(M x K) * W(N x K)^T + bias ----------------
// MODE 0: qkv -> scatter bf16 into Q,K,V [b][h][n][d]
// MODE 1: out -> f32 C row-major with bias
template <int MODE>
__global__ __launch_bounds__(256) void k_gemm(const u16* __restrict__ A,
                                              const u16* __restrict__ Bm,
                                              const float* __restrict__ bias,
                                              u16* __restrict__ Qo, u16* __restrict__ Ko,
                                              u16* __restrict__ Vo, float* __restrict__ Co,
                                              int K) {
  __shared__ u16 Al[128 * 36];
  __shared__ u16 Bl[128 * 36];
  const int t = threadIdx.x;
  const int lane = t & 63, wid = t >> 6;
  const int g = lane >> 4, i16 = lane & 15;
  const int wm = wid >> 1, wn = wid & 1;
  const int bm = blockIdx.y, bn = blockIdx.x;

  f32x4 zero = {0.f, 0.f, 0.f, 0.f};
  f32x4 acc[4][4];
#pragma unroll
  for (int mi = 0; mi < 4; ++mi)
#pragma unroll
    for (int ni = 0; ni < 4; ++ni) acc[mi][ni] = zero;

  const int r0 = t >> 2, c8 = (t & 3) * 8;
  const u16* Ag = A + (size_t)(bm * 128 + r0) * K + c8;
  const u16* Bg = Bm + (size_t)(bn * 128 + r0) * K + c8;

  for (int k0 = 0; k0 < K; k0 += 32) {
    __syncthreads();
    U8 a0, a1, b0, b1;
    a0.u4 = *(const uint4*)(Ag + k0);
    a1.u4 = *(const uint4*)(Ag + k0 + (size_t)64 * K);
    b0.u4 = *(const uint4*)(Bg + k0);
    b1.u4 = *(const uint4*)(Bg + k0 + (size_t)64 * K);
    *(uint2*)(Al + r0 * 36 + c8) = a0.u2[0];
    *(uint2*)(Al + r0 * 36 + c8 + 4) = a0.u2[1];
    *(uint2*)(Al + (r0 + 64) * 36 + c8) = a1.u2[0];
    *(uint2*)(Al + (r0 + 64) * 36 + c8 + 4) = a1.u2[1];
    *(uint2*)(Bl + r0 * 36 + c8) = b0.u2[0];
    *(uint2*)(Bl + r0 * 36 + c8 + 4) = b0.u2[1];
    *(uint2*)(Bl + (r0 + 64) * 36 + c8) = b1.u2[0];
    *(uint2*)(Bl + (r0 + 64) * 36 + c8 + 4) = b1.u2[1];
    __syncthreads();

    U8 af[4], bfg[4];
#pragma unroll
    for (int mi = 0; mi < 4; ++mi) {
      const u16* p = Al + (wm * 64 + mi * 16 + i16) * 36 + 8 * g;
      af[mi].u2[0] = *(const uint2*)p;
      af[mi].u2[1] = *(const uint2*)(p + 4);
    }
#pragma unroll
    for (int ni = 0; ni < 4; ++ni) {
      const u16* p = Bl + (wn * 64 + ni * 16 + i16) * 36 + 8 * g;
      bfg[ni].u2[0] = *(const uint2*)p;
      bfg[ni].u2[1] = *(const uint2*)(p + 4);
    }
#pragma unroll
    for (int mi = 0; mi < 4; ++mi)
#pragma unroll
      for (int ni = 0; ni < 4; ++ni)
        acc[mi][ni] = __builtin_amdgcn_mfma_f32_16x16x32_bf16(af[mi].b, bfg[ni].b,
                                                              acc[mi][ni], 0, 0, 0);
  }

#pragma unroll
  for (int mi = 0; mi < 4; ++mi) {
#pragma unroll
    for (int ni = 0; ni < 4; ++ni) {
      int colb = bn * 128 + wn * 64 + ni * 16;
      int col = colb + i16;
#pragma unroll
      for (int j = 0; j < 4; ++j) {
        int row = bm * 128 + wm * 64 + mi * 16 + 4 * g + j;
        float v = acc[mi][ni][j] + bias[col];
        if (MODE == 0) {
          int tt = col >> 10;
          int h = (col >> 6) & 15;
          int d = col & 63;
          int b = row >> 9;
          int n = row & 511;
          u16* dst = (tt == 0) ? Qo : ((tt == 1) ? Ko : Vo);
          dst[((size_t)(b * 16 + h) * 512 + n) * 64 + d] = f2bf(v);
        } else {
          Co[(size_t)row * 1024 + col] = v;
        }
      }
    }
  }
}

// ---------------- fused attention: softmax(Q K^T * scale + rel) V ----------------
// grid (qt=8, h=16, b=8), 256 threads = 4 waves, each wave owns 16 q-rows.
__global__ __launch_bounds__(256) void k_attn(const u16* __restrict__ Q,
                                              const u16* __restrict__ Kb,
                                              const u16* __restrict__ Vb,
                                              const u16* __restrict__ Rel,
                                              u16* __restrict__ Out) {
  __shared__ u16 Kl[64 * 68];
  __shared__ u16 Vt[64 * 68];
  __shared__ u16 Pl[4][16 * 68];

  const int qt = blockIdx.x, h = blockIdx.y, b = blockIdx.z;
  const int t = threadIdx.x, lane = t & 63, wid = t >> 6;
  const int g = lane >> 4, i16 = lane & 15;
  const size_t bh = (size_t)(b * 16 + h);

  // Q fragments (held in registers for entire kernel)
  const u16* Qg = Q + (bh * 512 + qt * 64 + wid * 16 + i16) * 64;
  U8 qf[2];
  qf[0].u4 = *(const uint4*)(Qg + 8 * g);
  qf[1].u4 = *(const uint4*)(Qg + 8 * g + 32);

  float m_run[4], l_run[4];
  f32x4 zero = {0.f, 0.f, 0.f, 0.f};
  f32x4 acc[4];
#pragma unroll
  for (int c = 0; c < 4; ++c) acc[c] = zero;
#pragma unroll
  for (int j = 0; j < 4; ++j) { m_run[j] = -1e30f; l_run[j] = 0.f; }

  const int r0 = t >> 2, c8 = (t & 3) * 8;
  const u16* Kg = Kb + (bh * 512 + r0) * 64 + c8;
  const u16* Vg = Vb + bh * 512 * 64;
  const u16* Rg = Rel + (bh * 512 + qt * 64 + wid * 16) * 512;

  for (int m0 = 0; m0 < 512; m0 += 64) {
    __syncthreads();
    // stage K tile [64 m][64 d] (row stride 68)
    {
      U8 u0, u1;
      u0.u4 = *(const uint4*)(Kg + m0 * 64);
      u1.u4 = *(const uint4*)(Kg + m0 * 64 + 32);
      *(uint2*)(Kl + r0 * 68 + c8) = u0.u2[0];
      *(uint2*)(Kl + r0 * 68 + c8 + 4) = u0.u2[1];
      *(uint2*)(Kl + r0 * 68 + c8 + 32) = u1.u2[0];
      *(uint2*)(Kl + r0 * 68 + c8 + 36) = u1.u2[1];
    }
    // stage V transposed: Vt[d][m_local] (row stride 68)
    {
      int d = t & 63, mg = t >> 6;
      u16 vr[16];
#pragma unroll
      for (int mm = 0; mm < 16; ++mm)
        vr[mm] = Vg[(size_t)(m0 + mg * 16 + mm) * 64 + d];
#pragma unroll
      for (int jj = 0; jj < 4; ++jj) {
        uint2 w;
        w.x = (u32)vr[4 * jj] | ((u32)vr[4 * jj + 1] << 16);
        w.y = (u32)vr[4 * jj + 2] | ((u32)vr[4 * jj + 3] << 16);
        *(uint2*)(Vt + d * 68 + mg * 16 + 4 * jj) = w;
      }
    }
    __syncthreads();

    // S = Q K^T  (per wave: 16 x 64)
    f32x4 s[4];
#pragma unroll
    for (int c = 0; c < 4; ++c) s[c] = zero;
#pragma unroll
    for (int c = 0; c < 4; ++c) {
#pragma unroll
      for (int kk = 0; kk < 2; ++kk) {
        U8 kf;
        const u16* p = Kl + (c * 16 + i16) * 68 + 8 * g + 32 * kk;
        kf.u2[0] = *(const uint2*)p;
        kf.u2[1] = *(const uint2*)(p + 4);
        s[c] = __builtin_amdgcn_mfma_f32_16x16x32_bf16(qf[kk].b, kf.b, s[c], 0, 0, 0);
      }
    }
    // scale + rel bias
#pragma unroll
    for (int c = 0; c < 4; ++c) {
#pragma unroll
      for (int j = 0; j < 4; ++j) {
        float rv = bf2f(Rg[(size_t)(4 * g + j) * 512 + m0 + c * 16 + i16]);
        s[c][j] = s[c][j] * 0.125f + rv;
      }
    }
    // online softmax (rows live across the 16 lanes sharing g)
    float fac[4];
#pragma unroll
    for (int j = 0; j < 4; ++j) {
      float pm = fmaxf(fmaxf(s[0][j], s[1][j]), fmaxf(s[2][j], s[3][j]));
      pm = fmaxf(pm, __shfl_xor(pm, 1));
      pm = fmaxf(pm, __shfl_xor(pm, 2));
      pm = fmaxf(pm, __shfl_xor(pm, 4));
      pm = fmaxf(pm, __shfl_xor(pm, 8));
      float mnew = fmaxf(m_run[j], pm);
      fac[j] = __expf(m_run[j] - mnew);
      m_run[j] = mnew;
    }
#pragma unroll
    for (int c = 0; c < 4; ++c)
#pragma unroll
      for (int j = 0; j < 4; ++j) s[c][j] = __expf(s[c][j] - m_run[j]);
#pragma unroll
    for (int j = 0; j < 4; ++j) {
      float rs = s[0][j] + s[1][j] + s[2][j] + s[3][j];
      rs += __shfl_xor(rs, 1);
      rs += __shfl_xor(rs, 2);
      rs += __shfl_xor(rs, 4);
      rs += __shfl_xor(rs, 8);
      l_run[j] = l_run[j] * fac[j] + rs;
    }
#pragma unroll
    for (int c = 0; c < 4; ++c)
#pragma unroll
      for (int j = 0; j < 4; ++j) acc[c][j] *= fac[j];

    // write P (bf16) to per-wave LDS region
    u16* Pw = Pl[wid];
#pragma unroll
    for (int c = 0; c < 4; ++c)
#pragma unroll
      for (int j = 0; j < 4; ++j)
        Pw[(4 * g + j) * 68 + c * 16 + i16] = f2bf(s[c][j]);
    __syncthreads();

    // O += P V
    U8 pf[2];
#pragma unroll
    for (int kk = 0; kk < 2; ++kk) {
      const u16* p = Pl[wid] + i16 * 68 + 8 * g + 32 * kk;
      pf[kk].u2[0] = *(const uint2*)p;
      pf[kk].u2[1] = *(const uint2*)(p + 4);
    }
#pragma unroll
    for (int c = 0; c < 4; ++c) {
#pragma unroll
      for (int kk = 0; kk < 2; ++kk) {
        U8 vf;
        const u16* p = Vt + (c * 16 + i16) * 68 + 8 * g + 32 * kk;
        vf.u2[0] = *(const uint2*)p;
        vf.u2[1] = *(const uint2*)(p + 4);
        acc[c] = __builtin_amdgcn_mfma_f32_16x16x32_bf16(pf[kk].b, vf.b, acc[c], 0, 0, 0);
      }
    }
  }

  // epilogue: normalize, write bf16 [b][n][h*64+d]
#pragma unroll
  for (int c = 0; c < 4; ++c) {
#pragma unroll
    for (int j = 0; j < 4; ++j) {
      int n = qt * 64 + wid * 16 + 4 * g + j;
      float v = acc[c][j] / l_run[j];
      Out[((size_t)b * 512 + n) * 1024 + h * 64 + c * 16 + i16] = f2bf(v);
    }
  }
}

// ---------------- launcher ----------------
extern "C" void kernel_launch(void* const* d_in, const int* in_sizes, int n_in,
                              void* d_out, int out_size, void* d_ws, size_t ws_size,
                              hipStream_t stream) {
  const float* x = (const float*)d_in[0];
  const float* rel_bias = (const float*)d_in[1];
  const float* W_qkv = (const float*)d_in[2];
  const float* b_qkv = (const float*)d_in[3];
  const float* W_rel = (const float*)d_in[4];
  const float* b_rel = (const float*)d_in[5];
  const float* W_out = (const float*)d_in[6];
  const float* b_out = (const float*)d_in[7];
  float* out = (float*)d_out;

  char* ws = (char*)d_ws;
  u16* x_bf    = (u16*)(ws);               //  8 MB  (4096x1024)
  u16* wqkv_bf = (u16*)(ws + 8388608);     //  6 MB  (3072x1024)
  u16* wout_bf = (u16*)(ws + 14680064);    //  2 MB  (1024x1024)
  u16* Qw      = (u16*)(ws + 16777216);    //  8 MB  [b][h][n][d]
  u16* Kw      = (u16*)(ws + 25165824);    //  8 MB
  u16* Vw      = (u16*)(ws + 33554432);    //  8 MB
  u16* relb    = (u16*)(ws + 41943040);    // 64 MB  [b][h][n][m]
  u16* attno   = (u16*)(ws + 109051904);   //  8 MB  (4096x1024)

  k_convert<<<2048, 256, 0, stream>>>(x, x_bf, 4194304 / 4);
  k_convert<<<1024, 256, 0, stream>>>(W_qkv, wqkv_bf, 3145728 / 4);
  k_convert<<<512, 256, 0, stream>>>(W_out, wout_bf, 1048576 / 4);

  k_rel<<<8192, 256, 0, stream>>>(rel_bias, W_rel, b_rel, relb);

  k_gemm<0><<<dim3(24, 32), 256, 0, stream>>>(x_bf, wqkv_bf, b_qkv, Qw, Kw, Vw, nullptr, 1024);

  k_attn<<<dim3(8, 16, 8), 256, 0, stream>>>(Qw, Kw, Vw, relb, attno);

  k_gemm<1><<<dim3(8, 32), 256, 0, stream>>>(attno, wout_bf, b_out, nullptr, nullptr, nullptr,
                                             out, 1024);
}

// Round 2
// 200.403 us; speedup vs baseline: 1.0588x; 1.0588x over previous
//
#include <hip/hip_runtime.h>

typedef unsigned short u16;
typedef unsigned int u32;
typedef __attribute__((ext_vector_type(8))) __bf16 bf16x8;
typedef __attribute__((ext_vector_type(4))) float f32x4;

union U8 {
  bf16x8 b;
  uint2 u2[2];
  uint4 u4;
  u16 us[8];
};

__device__ __forceinline__ u16 f2bf(float f) {
  u32 x = __float_as_uint(f);
  x += 0x7FFFu + ((x >> 16) & 1u);
  return (u16)(x >> 16);
}
__device__ __forceinline__ float bf2f(u16 u) {
  return __uint_as_float(((u32)u) << 16);
}

// async global->LDS, 16B per lane. LDS dest = wave-uniform base + lane*16.
#define GLOAD16(gp, lp)                                                          \
  __builtin_amdgcn_global_load_lds(                                              \
      (const __attribute__((address_space(1))) unsigned int*)(const void*)(gp),  \
      (__attribute__((address_space(3))) unsigned int*)(void*)(lp), 16, 0, 0)

// ---------------- f32 -> bf16 convert (vectorized) ----------------
__global__ void k_convert(const float* __restrict__ src, u16* __restrict__ dst, int n4) {
  int idx = blockIdx.x * blockDim.x + threadIdx.x;
  int stride = gridDim.x * blockDim.x;
  for (int i = idx; i < n4; i += stride) {
    float4 v = ((const float4*)src)[i];
    ushort4 o;
    o.x = f2bf(v.x); o.y = f2bf(v.y); o.z = f2bf(v.z); o.w = f2bf(v.w);
    ((ushort4*)dst)[i] = o;
  }
}

// ---------------- rel projection: (B*N*N, 32) @ (32,16)^T + b -> bf16 [b][h][n][m] ----------------
// HBM-bound: 268 MB read + 64 MB write ~= 50 us floor.
__global__ __launch_bounds__(256) void k_rel(const float* __restrict__ rb,
                                             const float* __restrict__ Wr,
                                             const float* __restrict__ br,
                                             u16* __restrict__ out) {
  __shared__ float Wl[16][32];
  __shared__ float bl[16];
  int t = threadIdx.x;
  ((float*)Wl)[t] = Wr[t];
  ((float*)Wl)[t + 256] = Wr[t + 256];
  if (t < 16) bl[t] = br[t];
  __syncthreads();

  size_t row = (size_t)blockIdx.x * 256 + t;  // < 2097152
  int m = (int)(row & 511);
  int n = (int)((row >> 9) & 511);
  int b = (int)(row >> 18);
  const float4* rp = (const float4*)(rb + row * 32);
  float4 r4[8];
#pragma unroll
  for (int j = 0; j < 8; ++j) r4[j] = rp[j];

  size_t obase = (size_t)b * 4194304 + (size_t)n * 512 + m;
#pragma unroll
  for (int h = 0; h < 16; ++h) {
    float acc = bl[h];
    const float* w = Wl[h];
#pragma unroll
    for (int j = 0; j < 8; ++j) {
      acc += r4[j].x * w[4 * j + 0] + r4[j].y * w[4 * j + 1] +
             r4[j].z * w[4 * j + 2] + r4[j].w * w[4 * j + 3];
    }
    out[obase + (size_t)h * 262144] = f2bf(acc);
  }
}

// ---------------- GEMM: C(M x N) = A(M x K) * W(N x K)^T + bias ----------------
// m97-style: 128x128 tile, BK=64, global_load_lds(16B) staging into linear LDS,
// both-sides XOR swizzle (global source chunk ^= r&7; ds_read chunk ^= row&7).
// MODE 0: qkv -> scatter bf16 into Q,K,V [b][h][n][d]
// MODE 1: out -> f32 C row-major with bias
template <int MODE>
__global__ __launch_bounds__(256) void k_gemm(const u16* __restrict__ A,
                                              const u16* __restrict__ Bm,
                                              const float* __restrict__ bias,
                                              u16* __restrict__ Qo, u16* __restrict__ Ko,
                                              u16* __restrict__ Vo, float* __restrict__ Co,
                                              int K) {
  __shared__ u16 Al[128 * 64];
  __shared__ u16 Bl[128 * 64];
  const int t = threadIdx.x;
  const int lane = t & 63, wid = t >> 6;
  const int g = lane >> 4, i16 = lane & 15;
  const int wm = wid >> 1, wn = wid & 1;
  const int bm = blockIdx.y, bn = blockIdx.x;

  f32x4 zero = {0.f, 0.f, 0.f, 0.f};
  f32x4 acc[4][4];
#pragma unroll
  for (int mi = 0; mi < 4; ++mi)
#pragma unroll
    for (int ni = 0; ni < 4; ++ni) acc[mi][ni] = zero;

  // staging: 1024 chunks of 16B per matrix; thread handles chunk ids wid*256+i*64+lane
  int srow[4], sgc[4];
#pragma unroll
  for (int i = 0; i < 4; ++i) {
    int ch = wid * 256 + i * 64 + lane;
    int r = ch >> 3, cs = ch & 7;
    srow[i] = r;
    sgc[i] = cs ^ (r & 7);
  }

  for (int k0 = 0; k0 < K; k0 += 64) {
    __syncthreads();
#pragma unroll
    for (int i = 0; i < 4; ++i) {
      const u16* ga = A + (size_t)(bm * 128 + srow[i]) * K + k0 + sgc[i] * 8;
      const u16* gb = Bm + (size_t)(bn * 128 + srow[i]) * K + k0 + sgc[i] * 8;
      u16* la = Al + (size_t)(wid * 256 + i * 64) * 8;
      u16* lb = Bl + (size_t)(wid * 256 + i * 64) * 8;
      GLOAD16(ga, la);
      GLOAD16(gb, lb);
    }
    __syncthreads();

#pragma unroll
    for (int kk = 0; kk < 2; ++kk) {
      U8 af[4], bfr[4];
#pragma unroll
      for (int mi = 0; mi < 4; ++mi) {
        int row = wm * 64 + mi * 16 + i16;
        int ch = (g + 4 * kk) ^ (row & 7);
        af[mi].u4 = *(const uint4*)(Al + row * 64 + ch * 8);
      }
#pragma unroll
      for (int ni = 0; ni < 4; ++ni) {
        int row = wn * 64 + ni * 16 + i16;
        int ch = (g + 4 * kk) ^ (row & 7);
        bfr[ni].u4 = *(const uint4*)(Bl + row * 64 + ch * 8);
      }
#pragma unroll
      for (int mi = 0; mi < 4; ++mi)
#pragma unroll
        for (int ni = 0; ni < 4; ++ni)
          acc[mi][ni] = __builtin_amdgcn_mfma_f32_16x16x32_bf16(af[mi].b, bfr[ni].b,
                                                                acc[mi][ni], 0, 0, 0);
    }
  }

#pragma unroll
  for (int mi = 0; mi < 4; ++mi) {
#pragma unroll
    for (int ni = 0; ni < 4; ++ni) {
      int colb = bn * 128 + wn * 64 + ni * 16;
      int col = colb + i16;
#pragma unroll
      for (int j = 0; j < 4; ++j) {
        int row = bm * 128 + wm * 64 + mi * 16 + 4 * g + j;
        float v = acc[mi][ni][j] + bias[col];
        if (MODE == 0) {
          int tt = col >> 10;
          int h = (col >> 6) & 15;
          int d = col & 63;
          int b = row >> 9;
          int n = row & 511;
          u16* dst = (tt == 0) ? Qo : ((tt == 1) ? Ko : Vo);
          dst[((size_t)(b * 16 + h) * 512 + n) * 64 + d] = f2bf(v);
        } else {
          Co[(size_t)row * 1024 + col] = v;
        }
      }
    }
  }
}

// ---------------- V transpose: [bh][n][d] -> [bh][d][n] (16 MB traffic, ~3 us) ----------------
__global__ __launch_bounds__(256) void k_vt(const u16* __restrict__ V, u16* __restrict__ Vt) {
  __shared__ u16 Tl[64][72];
  const int t = threadIdx.x;
  const int n0 = blockIdx.x * 64;
  const size_t bh = blockIdx.y;
#pragma unroll
  for (int i = 0; i < 2; ++i) {
    int c = i * 256 + t;
    int r = c >> 3, c8 = (c & 7) * 8;
    U8 v;
    v.u4 = *(const uint4*)(V + (bh * 512 + n0 + r) * 64 + c8);
    *(uint2*)&Tl[r][c8] = v.u2[0];
    *(uint2*)&Tl[r][c8 + 4] = v.u2[1];
  }
  __syncthreads();
#pragma unroll
  for (int i = 0; i < 2; ++i) {
    int c = i * 256 + t;
    int d = c >> 3, n8 = (c & 7) * 8;
    U8 o;
#pragma unroll
    for (int j = 0; j < 8; ++j) o.us[j] = Tl[n8 + j][d];
    *(uint4*)(Vt + (bh * 64 + d) * 512 + n0 + n8) = o.u4;
  }
}

// ---------------- fused attention: softmax(Q K^T * scale + rel) V ----------------
// grid (qt=8, h=16, b=8), 256 threads = 4 waves, each wave owns 16 q-rows.
// K and Vt tiles staged via global_load_lds with both-sides XOR swizzle.
__global__ __launch_bounds__(256) void k_attn(const u16* __restrict__ Q,
                                              const u16* __restrict__ Kb,
                                              const u16* __restrict__ Vtb,
                                              const u16* __restrict__ Rel,
                                              u16* __restrict__ Out) {
  __shared__ u16 Kl[64 * 64];
  __shared__ u16 Vl[64 * 64];
  __shared__ u16 Pl[4][16 * 68];

  const int qt = blockIdx.x, h = blockIdx.y, b = blockIdx.z;
  const int t = threadIdx.x, lane = t & 63, wid = t >> 6;
  const int g = lane >> 4, i16 = lane & 15;
  const size_t bh = (size_t)(b * 16 + h);

  // Q fragments (held in registers for entire kernel)
  const u16* Qg = Q + (bh * 512 + qt * 64 + wid * 16 + i16) * 64;
  U8 qf[2];
  qf[0].u4 = *(const uint4*)(Qg + 8 * g);
  qf[1].u4 = *(const uint4*)(Qg + 8 * g + 32);

  float m_run[4], l_run[4];
  f32x4 zero = {0.f, 0.f, 0.f, 0.f};
  f32x4 acc[4];
#pragma unroll
  for (int c = 0; c < 4; ++c) acc[c] = zero;
#pragma unroll
  for (int j = 0; j < 4; ++j) { m_run[j] = -1e30f; l_run[j] = 0.f; }

  // staging: 512 chunks per tile; thread handles chunk ids wid*128+i*64+lane
  int srow[2], sgc[2];
#pragma unroll
  for (int i = 0; i < 2; ++i) {
    int ch = wid * 128 + i * 64 + lane;
    int r = ch >> 3, cs = ch & 7;
    srow[i] = r;
    sgc[i] = cs ^ (r & 7);
  }

  const u16* Kg0 = Kb + bh * 512 * 64;
  const u16* Vg0 = Vtb + bh * 64 * 512;
  const u16* Rg = Rel + (bh * 512 + qt * 64 + wid * 16) * 512;

  for (int m0 = 0; m0 < 512; m0 += 64) {
    __syncthreads();
#pragma unroll
    for (int i = 0; i < 2; ++i) {
      u16* lbase = (u16*)0 + (size_t)(wid * 128 + i * 64) * 8;
      GLOAD16(Kg0 + (size_t)(m0 + srow[i]) * 64 + sgc[i] * 8, Kl + (size_t)(wid * 128 + i * 64) * 8);
      GLOAD16(Vg0 + (size_t)srow[i] * 512 + m0 + sgc[i] * 8, Vl + (size_t)(wid * 128 + i * 64) * 8);
      (void)lbase;
    }
    __syncthreads();

    // S = Q K^T  (per wave: 16 x 64)
    f32x4 s[4];
#pragma unroll
    for (int c = 0; c < 4; ++c) s[c] = zero;
#pragma unroll
    for (int c = 0; c < 4; ++c) {
#pragma unroll
      for (int kk = 0; kk < 2; ++kk) {
        int row = c * 16 + i16;
        int ch = (g + 4 * kk) ^ (row & 7);
        U8 kf;
        kf.u4 = *(const uint4*)(Kl + row * 64 + ch * 8);
        s[c] = __builtin_amdgcn_mfma_f32_16x16x32_bf16(qf[kk].b, kf.b, s[c], 0, 0, 0);
      }
    }
    // scale + rel bias
#pragma unroll
    for (int c = 0; c < 4; ++c) {
#pragma unroll
      for (int j = 0; j < 4; ++j) {
        float rv = bf2f(Rg[(size_t)(4 * g + j) * 512 + m0 + c * 16 + i16]);
        s[c][j] = s[c][j] * 0.125f + rv;
      }
    }
    // online softmax (rows live across the 16 lanes sharing g)
    float fac[4];
#pragma unroll
    for (int j = 0; j < 4; ++j) {
      float pm = fmaxf(fmaxf(s[0][j], s[1][j]), fmaxf(s[2][j], s[3][j]));
      pm = fmaxf(pm, __shfl_xor(pm, 1));
      pm = fmaxf(pm, __shfl_xor(pm, 2));
      pm = fmaxf(pm, __shfl_xor(pm, 4));
      pm = fmaxf(pm, __shfl_xor(pm, 8));
      float mnew = fmaxf(m_run[j], pm);
      fac[j] = __expf(m_run[j] - mnew);
      m_run[j] = mnew;
    }
#pragma unroll
    for (int c = 0; c < 4; ++c)
#pragma unroll
      for (int j = 0; j < 4; ++j) s[c][j] = __expf(s[c][j] - m_run[j]);
#pragma unroll
    for (int j = 0; j < 4; ++j) {
      float rs = s[0][j] + s[1][j] + s[2][j] + s[3][j];
      rs += __shfl_xor(rs, 1);
      rs += __shfl_xor(rs, 2);
      rs += __shfl_xor(rs, 4);
      rs += __shfl_xor(rs, 8);
      l_run[j] = l_run[j] * fac[j] + rs;
    }
#pragma unroll
    for (int c = 0; c < 4; ++c)
#pragma unroll
      for (int j = 0; j < 4; ++j) acc[c][j] *= fac[j];

    // write P (bf16) to per-wave LDS region
    u16* Pw = Pl[wid];
#pragma unroll
    for (int c = 0; c < 4; ++c)
#pragma unroll
      for (int j = 0; j < 4; ++j)
        Pw[(4 * g + j) * 68 + c * 16 + i16] = f2bf(s[c][j]);
    __syncthreads();

    // O += P V
    U8 pf[2];
#pragma unroll
    for (int kk = 0; kk < 2; ++kk) {
      const u16* p = Pl[wid] + i16 * 68 + 8 * g + 32 * kk;
      pf[kk].u2[0] = *(const uint2*)p;
      pf[kk].u2[1] = *(const uint2*)(p + 4);
    }
#pragma unroll
    for (int c = 0; c < 4; ++c) {
#pragma unroll
      for (int kk = 0; kk < 2; ++kk) {
        int row = c * 16 + i16;
        int ch = (g + 4 * kk) ^ (row & 7);
        U8 vf;
        vf.u4 = *(const uint4*)(Vl + row * 64 + ch * 8);
        acc[c] = __builtin_amdgcn_mfma_f32_16x16x32_bf16(pf[kk].b, vf.b, acc[c], 0, 0, 0);
      }
    }
  }

  // epilogue: normalize, write bf16 [b][n][h*64+d]
#pragma unroll
  for (int c = 0; c < 4; ++c) {
#pragma unroll
    for (int j = 0; j < 4; ++j) {
      int n = qt * 64 + wid * 16 + 4 * g + j;
      float v = acc[c][j] / l_run[j];
      Out[((size_t)b * 512 + n) * 1024 + h * 64 + c * 16 + i16] = f2bf(v);
    }
  }
}

// ---------------- launcher ----------------
extern "C" void kernel_launch(void* const* d_in, const int* in_sizes, int n_in,
                              void* d_out, int out_size, void* d_ws, size_t ws_size,
                              hipStream_t stream) {
  const float* x = (const float*)d_in[0];
  const float* rel_bias = (const float*)d_in[1];
  const float* W_qkv = (const float*)d_in[2];
  const float* b_qkv = (const float*)d_in[3];
  const float* W_rel = (const float*)d_in[4];
  const float* b_rel = (const float*)d_in[5];
  const float* W_out = (const float*)d_in[6];
  const float* b_out = (const float*)d_in[7];
  float* out = (float*)d_out;

  char* ws = (char*)d_ws;
  u16* x_bf    = (u16*)(ws);               //  8 MB  (4096x1024); dead after qkv gemm
  u16* Vt      = (u16*)(ws);               //  8 MB  [b][h][d][n] — reuses x_bf region
  u16* wqkv_bf = (u16*)(ws + 8388608);     //  6 MB  (3072x1024)
  u16* wout_bf = (u16*)(ws + 14680064);    //  2 MB  (1024x1024)
  u16* Qw      = (u16*)(ws + 16777216);    //  8 MB  [b][h][n][d]
  u16* Kw      = (u16*)(ws + 25165824);    //  8 MB
  u16* Vw      = (u16*)(ws + 33554432);    //  8 MB
  u16* relb    = (u16*)(ws + 41943040);    // 64 MB  [b][h][n][m]
  u16* attno   = (u16*)(ws + 109051904);   //  8 MB  (4096x1024)

  k_convert<<<2048, 256, 0, stream>>>(x, x_bf, 4194304 / 4);
  k_convert<<<1024, 256, 0, stream>>>(W_qkv, wqkv_bf, 3145728 / 4);
  k_convert<<<512, 256, 0, stream>>>(W_out, wout_bf, 1048576 / 4);

  k_rel<<<8192, 256, 0, stream>>>(rel_bias, W_rel, b_rel, relb);

  k_gemm<0><<<dim3(24, 32), 256, 0, stream>>>(x_bf, wqkv_bf, b_qkv, Qw, Kw, Vw, nullptr, 1024);

  k_vt<<<dim3(8, 128), 256, 0, stream>>>(Vw, Vt);  // overwrites x_bf (dead)

  k_attn<<<dim3(8, 16, 8), 256, 0, stream>>>(Qw, Kw, Vt, relb, attno);

  k_gemm<1><<<dim3(8, 32), 256, 0, stream>>>(attno, wout_bf, b_out, nullptr, nullptr, nullptr,
                                             out, 1024);
}